// Round 6
// baseline (401.625 us; speedup 1.0000x reference)
//
#include <hip/hip_runtime.h>
#include <hip/hip_bf16.h>

#define CCH 128
#define HGT 256
#define WID 256
#define HW  65536

typedef __attribute__((ext_vector_type(8))) short short8;
typedef __attribute__((ext_vector_type(4))) float floatx4;

// ws layout:
//   floats [0,512)     sum_h (4*128)
//   floats [512,1024)  sum_v
//   floats [1024,1032) wgate (4*2)
//   byte 32768:        hbuf bf16 (4*128*65536)
//   then               vbuf bf16

__device__ __forceinline__ float bf2f(unsigned short u) {
  return __uint_as_float(((unsigned)u) << 16);
}
__device__ __forceinline__ short f2bfs(float f) {
  return (short)__bfloat16_as_ushort(__float2bfloat16(f));
}

// Merged directional conv, 16384 blocks: first 8192 horizontal (16 rows x
// 256 px, 16 px/thread), rest vertical (16 rows x 256 cols, 2 cols x 8 y
// per thread, float2 loads). __launch_bounds__(256,4): min 4 waves/EU ->
// VGPR cap 128 AND scheduler occupancy target 4 waves/EU, so the 30-deep
// load batches stay live instead of the round-5 VGPR=40 serialized chains.
__global__ __launch_bounds__(256, 4) void conv_kernel(
    const float* __restrict__ x,
    const float* __restrict__ h1w, const float* __restrict__ h2w,
    const float* __restrict__ v1w, const float* __restrict__ v2w,
    __hip_bfloat16* __restrict__ hbuf, __hip_bfloat16* __restrict__ vbuf,
    float* __restrict__ sum_h, float* __restrict__ sum_v) {
  int d = blockIdx.x;
  int l = (d & 7) * 2048 + (d >> 3);   // bijective XCD chunking: 16384 % 8 == 0
  int t = threadIdx.x;
  float acc = 0.f;
  int bcg;
  float* sums;
  if (l < 8192) {
    // ---- horizontal: block = (b,c, 16-row tile); thread = 16 consecutive px
    int bc = l >> 4;
    int c = bc & (CCH - 1);
    int row = (l & 15) * 16 + (t >> 4);
    int p0 = (t & 15) * 16;
    const float* xr = x + (size_t)bc * HW + (size_t)row * WID;
    float w1[5], w2[7];
#pragma unroll
    for (int i = 0; i < 5; ++i) w1[i] = h1w[c * 5 + i];
#pragma unroll
    for (int j = 0; j < 7; ++j) w2[j] = h2w[c * 7 + j];
    float xv[40];
#pragma unroll
    for (int k = 0; k < 10; ++k) {
      int col = p0 - 12 + 4 * k;
      float4 v = make_float4(0.f, 0.f, 0.f, 0.f);
      if (col >= 0 && col < WID) v = *(const float4*)(xr + col);
      xv[4 * k] = v.x; xv[4 * k + 1] = v.y; xv[4 * k + 2] = v.z; xv[4 * k + 3] = v.w;
    }
    float s1[34];
#pragma unroll
    for (int m = 0; m < 34; ++m) {
      int q = p0 - 9 + m;
      float s = 0.f;
#pragma unroll
      for (int i = 0; i < 5; ++i) s = fmaf(xv[m + 1 + i], w1[i], s);
      s1[m] = ((unsigned)q < (unsigned)WID) ? s : 0.f;
    }
    short8 st0, st1;
#pragma unroll
    for (int u = 0; u < 16; ++u) {
      float s = 0.f;
#pragma unroll
      for (int j = 0; j < 7; ++j) s = fmaf(s1[u + 3 * j], w2[j], s);
      if (u < 8) st0[u] = f2bfs(s); else st1[u - 8] = f2bfs(s);
      acc += s;
    }
    unsigned short* hp = (unsigned short*)hbuf + (size_t)bc * HW + (size_t)row * WID + p0;
    *(short8*)hp = st0;
    *(short8*)(hp + 8) = st1;
    bcg = bc; sums = sum_h;
  } else {
    // ---- vertical: block = (b,c, 16-row tile); thread = 2 cols x 8 y's
    int lb = l - 8192;
    int bc = lb >> 4;
    int c = bc & (CCH - 1);
    int cp = (t & 127) * 2;
    int y0 = (lb & 15) * 16 + (t >> 7) * 8;
    const float* xc = x + (size_t)bc * HW + cp;
    float w1[5], w2[7];
#pragma unroll
    for (int i = 0; i < 5; ++i) w1[i] = v1w[c * 5 + i];
#pragma unroll
    for (int j = 0; j < 7; ++j) w2[j] = v2w[c * 7 + j];
    float2 xq[30];
#pragma unroll
    for (int m = 0; m < 30; ++m) {
      int yy = y0 - 11 + m;
      xq[m] = ((unsigned)yy < (unsigned)HGT) ? *(const float2*)(xc + (size_t)yy * WID)
                                             : make_float2(0.f, 0.f);
    }
    ushort2 res[8];
#pragma unroll
    for (int cc = 0; cc < 2; ++cc) {
      float s1[26];
#pragma unroll
      for (int m = 0; m < 26; ++m) {
        int q = y0 - 9 + m;
        float s = 0.f;
#pragma unroll
        for (int i = 0; i < 5; ++i) {
          float xv = (cc == 0) ? xq[m + i].x : xq[m + i].y;
          s = fmaf(xv, w1[i], s);
        }
        s1[m] = ((unsigned)q < (unsigned)HGT) ? s : 0.f;
      }
#pragma unroll
      for (int u = 0; u < 8; ++u) {
        float s = 0.f;
#pragma unroll
        for (int j = 0; j < 7; ++j) s = fmaf(s1[u + 3 * j], w2[j], s);
        unsigned short bs = (unsigned short)f2bfs(s);
        if (cc == 0) res[u].x = bs; else res[u].y = bs;
        acc += s;
      }
    }
    unsigned short* vp = (unsigned short*)vbuf + (size_t)bc * HW + cp;
#pragma unroll
    for (int u = 0; u < 8; ++u)
      *(ushort2*)(vp + (size_t)(y0 + u) * WID) = res[u];
    bcg = bc; sums = sum_v;
  }
#pragma unroll
  for (int off = 32; off > 0; off >>= 1) acc += __shfl_down(acc, off);
  if ((t & 63) == 0) atomicAdd(&sums[bcg], acc);
}

// single block: pooled -> g1 -> SiLU -> g2 -> softmax
__global__ __launch_bounds__(128) void gate_kernel(
    const float* __restrict__ sum_h, const float* __restrict__ sum_v,
    const float* __restrict__ g1w, const float* __restrict__ g2w,
    const float* __restrict__ g2b, float* __restrict__ wgate) {
  int t = threadIdx.x;
  __shared__ float gs[4][32];
  int b = t >> 5, r = t & 31;
  {
    float acc = 0.f;
    const float inv = 1.f / 65536.f;
    for (int k = 0; k < 128; ++k)
      acc = fmaf(sum_h[b * 128 + k] * inv, g1w[r * 256 + k], acc);
    for (int k = 0; k < 128; ++k)
      acc = fmaf(sum_v[b * 128 + k] * inv, g1w[r * 256 + 128 + k], acc);
    float sig = 1.f / (1.f + expf(-acc));
    gs[b][r] = acc * sig;
  }
  __syncthreads();
  if (t < 4) {
    float t0 = g2b[0], t1 = g2b[1];
    for (int rr = 0; rr < 32; ++rr) {
      t0 = fmaf(gs[t][rr], g2w[rr], t0);
      t1 = fmaf(gs[t][rr], g2w[32 + rr], t1);
    }
    float mx = fmaxf(t0, t1);
    float e0 = expf(t0 - mx), e1 = expf(t1 - mx);
    float inv = 1.f / (e0 + e1);
    wgate[t * 2 + 0] = e0 * inv;
    wgate[t * 2 + 1] = e1 * inv;
  }
}

// MFMA fuse (FROZEN from round 5): one block per (b, y, half).
__global__ __launch_bounds__(256, 4) void fuse_kernel(
    const float* __restrict__ x, const __hip_bfloat16* __restrict__ hbuf,
    const __hip_bfloat16* __restrict__ vbuf, const float* __restrict__ fuse_w,
    const float* __restrict__ fuse_b, const float* __restrict__ wgate,
    float* __restrict__ out) {
  __shared__ unsigned short aT[128 * 128];  // swizzled [p][c'] bf16, 32 KB
  int bid = blockIdx.x;        // (b*256 + y)*2 + half
  int half = bid & 1;
  int y = (bid >> 1) & 255;
  int b = bid >> 9;
  int t = threadIdx.x;
  int w = t >> 6, lane = t & 63;
  int quad = lane >> 4, n16 = lane & 15;
  float wh = wgate[b * 2], wv = wgate[b * 2 + 1];

  size_t base = (size_t)(b * CCH) * HW + (size_t)y * WID + half * 128;
  const unsigned short* hb = (const unsigned short*)hbuf;
  const unsigned short* vb = (const unsigned short*)vbuf;
  int cth = t >> 4;
  int p0 = (t & 15) * 8;

  // (1) issue ALL staging loads first
  short8 hv[16];
#pragma unroll
  for (int cpass = 0; cpass < 8; ++cpass) {
    int c = cpass * 16 + cth;
    size_t gi = base + (size_t)c * HW + p0;
    hv[2 * cpass]     = *(const short8*)(hb + gi);
    hv[2 * cpass + 1] = *(const short8*)(vb + gi);
  }
  // combine + transposed swizzled ds_write
#pragma unroll
  for (int cpass = 0; cpass < 8; ++cpass) {
    int c = cpass * 16 + cth;
    int g = c >> 3, c7 = c & 7;
#pragma unroll
    for (int e = 0; e < 8; ++e) {
      float a = fmaf(wh, bf2f((unsigned short)hv[2 * cpass][e]),
                     wv * bf2f((unsigned short)hv[2 * cpass + 1][e]));
      int p = p0 + e;
      int gp = g ^ (p & 15) ^ (p >> 4);
      aT[p * 128 + gp * 8 + c7] = (unsigned short)f2bfs(a);
    }
  }

  // (2) W fragments (B-operand), loaded while waiting for the barrier
  short8 wf[2][4];
#pragma unroll
  for (int ni = 0; ni < 2; ++ni) {
    int o = (2 * w + ni) * 16 + n16;
#pragma unroll
    for (int kt = 0; kt < 4; ++kt) {
      const float* wp = fuse_w + o * 128 + kt * 32 + quad * 8;
      float4 f0 = *(const float4*)wp;
      float4 f1 = *(const float4*)(wp + 4);
      short8 s;
      s[0] = f2bfs(f0.x); s[1] = f2bfs(f0.y); s[2] = f2bfs(f0.z); s[3] = f2bfs(f0.w);
      s[4] = f2bfs(f1.x); s[5] = f2bfs(f1.y); s[6] = f2bfs(f1.z); s[7] = f2bfs(f1.w);
      wf[ni][kt] = s;
    }
  }
  __syncthreads();

  // MFMA: acc[mt][ni] = D[p-tile mt][o-tile 2w+ni]
  floatx4 acc[8][2];
#pragma unroll
  for (int mt = 0; mt < 8; ++mt)
#pragma unroll
    for (int ni = 0; ni < 2; ++ni) acc[mt][ni] = (floatx4)0.f;

#pragma unroll
  for (int kt = 0; kt < 4; ++kt) {
#pragma unroll
    for (int mt = 0; mt < 8; ++mt) {
      int p = mt * 16 + n16;
      int gp = (4 * kt + quad) ^ (p & 15) ^ (p >> 4);
      short8 afr = *(const short8*)&aT[p * 128 + gp * 8];
      acc[mt][0] = __builtin_amdgcn_mfma_f32_16x16x32_bf16(afr, wf[0][kt], acc[mt][0], 0, 0, 0);
      acc[mt][1] = __builtin_amdgcn_mfma_f32_16x16x32_bf16(afr, wf[1][kt], acc[mt][1], 0, 0, 0);
    }
  }

  // epilogue: lane holds p = mt*16 + quad*4 + r (r=0..3), o = (2w+ni)*16+n16
  float fb0 = fuse_b[(2 * w) * 16 + n16];
  float fb1 = fuse_b[(2 * w + 1) * 16 + n16];
  size_t ob0 = base + (size_t)((2 * w) * 16 + n16) * HW;
  size_t ob1 = base + (size_t)((2 * w + 1) * 16 + n16) * HW;
#pragma unroll
  for (int mt = 0; mt < 8; ++mt) {
    int pq = mt * 16 + quad * 4;
    float4 x0 = *(const float4*)(x + ob0 + pq);
    float4 x1 = *(const float4*)(x + ob1 + pq);
    floatx4 a0 = acc[mt][0], a1 = acc[mt][1];
    float4 r0, r1;
    r0.x = x0.x * fmaf(0.5f, fb0 + a0[0], 0.5f);
    r0.y = x0.y * fmaf(0.5f, fb0 + a0[1], 0.5f);
    r0.z = x0.z * fmaf(0.5f, fb0 + a0[2], 0.5f);
    r0.w = x0.w * fmaf(0.5f, fb0 + a0[3], 0.5f);
    r1.x = x1.x * fmaf(0.5f, fb1 + a1[0], 0.5f);
    r1.y = x1.y * fmaf(0.5f, fb1 + a1[1], 0.5f);
    r1.z = x1.z * fmaf(0.5f, fb1 + a1[2], 0.5f);
    r1.w = x1.w * fmaf(0.5f, fb1 + a1[3], 0.5f);
    *(float4*)(out + ob0 + pq) = r0;
    *(float4*)(out + ob1 + pq) = r1;
  }
}

extern "C" void kernel_launch(void* const* d_in, const int* in_sizes, int n_in,
                              void* d_out, int out_size, void* d_ws, size_t ws_size,
                              hipStream_t stream) {
  const float* x      = (const float*)d_in[0];
  const float* h1w    = (const float*)d_in[1];
  const float* h2w    = (const float*)d_in[2];
  const float* v1w    = (const float*)d_in[3];
  const float* v2w    = (const float*)d_in[4];
  const float* g1w    = (const float*)d_in[5];
  const float* g2w    = (const float*)d_in[6];
  const float* g2b    = (const float*)d_in[7];
  const float* fusew  = (const float*)d_in[8];
  const float* fuseb  = (const float*)d_in[9];
  float* out = (float*)d_out;

  float* sums  = (float*)d_ws;       // sum_h(512), sum_v(512), wgate(8)
  float* sum_h = sums;
  float* sum_v = sums + 512;
  float* wgate = sums + 1024;
  __hip_bfloat16* hbuf = (__hip_bfloat16*)((char*)d_ws + 32768);
  __hip_bfloat16* vbuf = hbuf + (size_t)4 * CCH * HW;

  hipMemsetAsync(d_ws, 0, 1032 * sizeof(float), stream);
  conv_kernel<<<16384, 256, 0, stream>>>(x, h1w, h2w, v1w, v2w, hbuf, vbuf, sum_h, sum_v);
  gate_kernel<<<1, 128, 0, stream>>>(sum_h, sum_v, g1w, g2w, g2b, wgate);
  fuse_kernel<<<4 * HGT * 2, 256, 0, stream>>>(x, hbuf, vbuf, fusew, fuseb, wgate, out);
}

// Round 7
// 376.074 us; speedup vs baseline: 1.0679x; 1.0679x over previous
//
#include <hip/hip_runtime.h>
#include <hip/hip_bf16.h>

#define CCH 128
#define HGT 256
#define WID 256
#define HW  65536

typedef __attribute__((ext_vector_type(8))) short short8;
typedef __attribute__((ext_vector_type(4))) float floatx4;

// ws layout:
//   floats [0,512)     sum_h (4*128)
//   floats [512,1024)  sum_v
//   byte 32768:        hbuf bf16 (4*128*65536)
//   then               vbuf bf16

__device__ __forceinline__ float bf2f(unsigned short u) {
  return __uint_as_float(((unsigned)u) << 16);
}
__device__ __forceinline__ short f2bfs(float f) {
  return (short)__bfloat16_as_ushort(__float2bfloat16(f));
}

// Merged directional conv, 12288 blocks — EXACT round-5 body (121 us,
// VGPR 40). Two failed attempts (r2 tile-grow, r6 launch-bounds hint) to
// steer regalloc into deeper load batches both regressed; keep this one.
__global__ __launch_bounds__(256) void conv_kernel(
    const float* __restrict__ x,
    const float* __restrict__ h1w, const float* __restrict__ h2w,
    const float* __restrict__ v1w, const float* __restrict__ v2w,
    __hip_bfloat16* __restrict__ hbuf, __hip_bfloat16* __restrict__ vbuf,
    float* __restrict__ sum_h, float* __restrict__ sum_v) {
  int d = blockIdx.x;
  int l = (d & 7) * 1536 + (d >> 3);   // bijective XCD chunking: 12288 % 8 == 0
  int t = threadIdx.x;
  float acc = 0.f;
  int bcg;
  float* sums;
  if (l < 8192) {
    // ---- horizontal: block = (b,c, 16-row tile); thread = 16 consecutive px
    int bc = l >> 4;
    int c = bc & (CCH - 1);
    int row = (l & 15) * 16 + (t >> 4);
    int p0 = (t & 15) * 16;
    const float* xr = x + (size_t)bc * HW + (size_t)row * WID;
    float w1[5], w2[7];
#pragma unroll
    for (int i = 0; i < 5; ++i) w1[i] = h1w[c * 5 + i];
#pragma unroll
    for (int j = 0; j < 7; ++j) w2[j] = h2w[c * 7 + j];
    float xv[40];
#pragma unroll
    for (int k = 0; k < 10; ++k) {
      int col = p0 - 12 + 4 * k;
      float4 v = make_float4(0.f, 0.f, 0.f, 0.f);
      if (col >= 0 && col < WID) v = *(const float4*)(xr + col);
      xv[4 * k] = v.x; xv[4 * k + 1] = v.y; xv[4 * k + 2] = v.z; xv[4 * k + 3] = v.w;
    }
    float s1[34];
#pragma unroll
    for (int m = 0; m < 34; ++m) {
      int q = p0 - 9 + m;
      float s = 0.f;
#pragma unroll
      for (int i = 0; i < 5; ++i) s = fmaf(xv[m + 1 + i], w1[i], s);
      s1[m] = ((unsigned)q < (unsigned)WID) ? s : 0.f;
    }
    short8 st0, st1;
#pragma unroll
    for (int u = 0; u < 16; ++u) {
      float s = 0.f;
#pragma unroll
      for (int j = 0; j < 7; ++j) s = fmaf(s1[u + 3 * j], w2[j], s);
      if (u < 8) st0[u] = f2bfs(s); else st1[u - 8] = f2bfs(s);
      acc += s;
    }
    unsigned short* hp = (unsigned short*)hbuf + (size_t)bc * HW + (size_t)row * WID + p0;
    *(short8*)hp = st0;
    *(short8*)(hp + 8) = st1;
    bcg = bc; sums = sum_h;
  } else {
    // ---- vertical: block = (b,c, 32-row tile); thread = one column, 32 y's
    int lb = l - 8192;
    int bc = lb >> 3;
    int c = bc & (CCH - 1);
    int y0 = (lb & 7) * 32;
    const float* xc = x + (size_t)bc * HW + t;
    float w1[5], w2[7];
#pragma unroll
    for (int i = 0; i < 5; ++i) w1[i] = v1w[c * 5 + i];
#pragma unroll
    for (int j = 0; j < 7; ++j) w2[j] = v2w[c * 7 + j];
    float xv[54];
#pragma unroll
    for (int m = 0; m < 54; ++m) {
      int yy = y0 - 11 + m;
      xv[m] = ((unsigned)yy < (unsigned)HGT) ? xc[(size_t)yy * WID] : 0.f;
    }
    float s1[50];
#pragma unroll
    for (int m = 0; m < 50; ++m) {
      int q = y0 - 9 + m;
      float s = 0.f;
#pragma unroll
      for (int i = 0; i < 5; ++i) s = fmaf(xv[m + i], w1[i], s);
      s1[m] = ((unsigned)q < (unsigned)HGT) ? s : 0.f;
    }
    unsigned short* vp = (unsigned short*)vbuf + (size_t)bc * HW + t;
#pragma unroll
    for (int u = 0; u < 32; ++u) {
      float s = 0.f;
#pragma unroll
      for (int j = 0; j < 7; ++j) s = fmaf(s1[u + 3 * j], w2[j], s);
      vp[(size_t)(y0 + u) * WID] = (unsigned short)f2bfs(s);
      acc += s;
    }
    bcg = bc; sums = sum_v;
  }
#pragma unroll
  for (int off = 32; off > 0; off >>= 1) acc += __shfl_down(acc, off);
  if ((t & 63) == 0) atomicAdd(&sums[bcg], acc);
}

// MFMA fuse (round-5 body) + in-kernel gate prologue. One block per
// (b, y, half). The 16 staging loads are issued FIRST (they don't depend on
// wh/wv), pinned by sched_barrier(0); the tiny gate MLP (from the 1KB
// sum_h/sum_v vectors, L2-hot) computes under their HBM latency. The first
// __syncthreads of the gate also drains vmcnt, so hv[] is ready when the
// combine starts. Removes the separate gate kernel launch entirely.
__global__ __launch_bounds__(256, 4) void fuse_kernel(
    const float* __restrict__ x, const __hip_bfloat16* __restrict__ hbuf,
    const __hip_bfloat16* __restrict__ vbuf, const float* __restrict__ fuse_w,
    const float* __restrict__ fuse_b, const float* __restrict__ g1w,
    const float* __restrict__ g2w, const float* __restrict__ g2b,
    const float* __restrict__ sum_h, const float* __restrict__ sum_v,
    float* __restrict__ out) {
  __shared__ unsigned short aT[128 * 128];  // swizzled [p][c'] bf16, 32 KB
  __shared__ float pool[256];
  __shared__ float gpart[256];
  __shared__ float wgs[2];
  int bid = blockIdx.x;        // (b*256 + y)*2 + half
  int half = bid & 1;
  int y = (bid >> 1) & 255;
  int b = bid >> 9;
  int t = threadIdx.x;
  int w = t >> 6, lane = t & 63;
  int quad = lane >> 4, n16 = lane & 15;

  size_t base = (size_t)(b * CCH) * HW + (size_t)y * WID + half * 128;
  const unsigned short* hb = (const unsigned short*)hbuf;
  const unsigned short* vb = (const unsigned short*)vbuf;
  int cth = t >> 4;
  int p0 = (t & 15) * 8;

  // (1) issue ALL staging loads first (independent of the gate)
  short8 hv[16];
#pragma unroll
  for (int cpass = 0; cpass < 8; ++cpass) {
    int c = cpass * 16 + cth;
    size_t gi = base + (size_t)c * HW + p0;
    hv[2 * cpass]     = *(const short8*)(hb + gi);
    hv[2 * cpass + 1] = *(const short8*)(vb + gi);
  }
  __builtin_amdgcn_sched_barrier(0);  // keep loads issued before gate code

  // (2) gate MLP under the loads' latency: pooled -> g1 -> SiLU -> g2 -> softmax
  const float ginv = 1.f / 65536.f;
  pool[t] = ((t < 128) ? sum_h[b * 128 + t] : sum_v[b * 128 + (t - 128)]) * ginv;
  __syncthreads();
  {
    int r = t >> 3, sg = t & 7;
    const float* wr = g1w + r * 256 + sg * 32;
    const float* pr = pool + sg * 32;
    float gp = 0.f;
#pragma unroll
    for (int i = 0; i < 32; ++i) gp = fmaf(pr[i], wr[i], gp);
    gpart[t] = gp;
  }
  __syncthreads();
  if (t < 64) {
    float z0c = 0.f, z1c = 0.f;
    if (t < 32) {
      float g = 0.f;
#pragma unroll
      for (int sg = 0; sg < 8; ++sg) g += gpart[t * 8 + sg];
      g = g * (1.f / (1.f + expf(-g)));
      z0c = g * g2w[t];
      z1c = g * g2w[32 + t];
    }
#pragma unroll
    for (int off = 32; off > 0; off >>= 1) {
      z0c += __shfl_down(z0c, off);
      z1c += __shfl_down(z1c, off);
    }
    if (t == 0) {
      float z0 = z0c + g2b[0], z1 = z1c + g2b[1];
      float mx = fmaxf(z0, z1);
      float e0 = expf(z0 - mx), e1 = expf(z1 - mx);
      float is = 1.f / (e0 + e1);
      wgs[0] = e0 * is;
      wgs[1] = e1 * is;
    }
  }
  __syncthreads();
  float wh = wgs[0], wv = wgs[1];

  // (3) combine + transposed swizzled ds_write
#pragma unroll
  for (int cpass = 0; cpass < 8; ++cpass) {
    int c = cpass * 16 + cth;
    int g = c >> 3, c7 = c & 7;
#pragma unroll
    for (int e = 0; e < 8; ++e) {
      float a = fmaf(wh, bf2f((unsigned short)hv[2 * cpass][e]),
                     wv * bf2f((unsigned short)hv[2 * cpass + 1][e]));
      int p = p0 + e;
      int gp = g ^ (p & 15) ^ (p >> 4);
      aT[p * 128 + gp * 8 + c7] = (unsigned short)f2bfs(a);
    }
  }

  // (4) W fragments (B-operand), loaded while waiting for the barrier
  short8 wf[2][4];
#pragma unroll
  for (int ni = 0; ni < 2; ++ni) {
    int o = (2 * w + ni) * 16 + n16;
#pragma unroll
    for (int kt = 0; kt < 4; ++kt) {
      const float* wp = fuse_w + o * 128 + kt * 32 + quad * 8;
      float4 f0 = *(const float4*)wp;
      float4 f1 = *(const float4*)(wp + 4);
      short8 s;
      s[0] = f2bfs(f0.x); s[1] = f2bfs(f0.y); s[2] = f2bfs(f0.z); s[3] = f2bfs(f0.w);
      s[4] = f2bfs(f1.x); s[5] = f2bfs(f1.y); s[6] = f2bfs(f1.z); s[7] = f2bfs(f1.w);
      wf[ni][kt] = s;
    }
  }
  __syncthreads();

  // MFMA: acc[mt][ni] = D[p-tile mt][o-tile 2w+ni]
  floatx4 acc[8][2];
#pragma unroll
  for (int mt = 0; mt < 8; ++mt)
#pragma unroll
    for (int ni = 0; ni < 2; ++ni) acc[mt][ni] = (floatx4)0.f;

#pragma unroll
  for (int kt = 0; kt < 4; ++kt) {
#pragma unroll
    for (int mt = 0; mt < 8; ++mt) {
      int p = mt * 16 + n16;
      int gp = (4 * kt + quad) ^ (p & 15) ^ (p >> 4);
      short8 afr = *(const short8*)&aT[p * 128 + gp * 8];
      acc[mt][0] = __builtin_amdgcn_mfma_f32_16x16x32_bf16(afr, wf[0][kt], acc[mt][0], 0, 0, 0);
      acc[mt][1] = __builtin_amdgcn_mfma_f32_16x16x32_bf16(afr, wf[1][kt], acc[mt][1], 0, 0, 0);
    }
  }

  // epilogue: lane holds p = mt*16 + quad*4 + r (r=0..3), o = (2w+ni)*16+n16
  float fb0 = fuse_b[(2 * w) * 16 + n16];
  float fb1 = fuse_b[(2 * w + 1) * 16 + n16];
  size_t ob0 = base + (size_t)((2 * w) * 16 + n16) * HW;
  size_t ob1 = base + (size_t)((2 * w + 1) * 16 + n16) * HW;
#pragma unroll
  for (int mt = 0; mt < 8; ++mt) {
    int pq = mt * 16 + quad * 4;
    float4 x0 = *(const float4*)(x + ob0 + pq);
    float4 x1 = *(const float4*)(x + ob1 + pq);
    floatx4 a0 = acc[mt][0], a1 = acc[mt][1];
    float4 r0, r1;
    r0.x = x0.x * fmaf(0.5f, fb0 + a0[0], 0.5f);
    r0.y = x0.y * fmaf(0.5f, fb0 + a0[1], 0.5f);
    r0.z = x0.z * fmaf(0.5f, fb0 + a0[2], 0.5f);
    r0.w = x0.w * fmaf(0.5f, fb0 + a0[3], 0.5f);
    r1.x = x1.x * fmaf(0.5f, fb1 + a1[0], 0.5f);
    r1.y = x1.y * fmaf(0.5f, fb1 + a1[1], 0.5f);
    r1.z = x1.z * fmaf(0.5f, fb1 + a1[2], 0.5f);
    r1.w = x1.w * fmaf(0.5f, fb1 + a1[3], 0.5f);
    *(float4*)(out + ob0 + pq) = r0;
    *(float4*)(out + ob1 + pq) = r1;
  }
}

extern "C" void kernel_launch(void* const* d_in, const int* in_sizes, int n_in,
                              void* d_out, int out_size, void* d_ws, size_t ws_size,
                              hipStream_t stream) {
  const float* x      = (const float*)d_in[0];
  const float* h1w    = (const float*)d_in[1];
  const float* h2w    = (const float*)d_in[2];
  const float* v1w    = (const float*)d_in[3];
  const float* v2w    = (const float*)d_in[4];
  const float* g1w    = (const float*)d_in[5];
  const float* g2w    = (const float*)d_in[6];
  const float* g2b    = (const float*)d_in[7];
  const float* fusew  = (const float*)d_in[8];
  const float* fuseb  = (const float*)d_in[9];
  float* out = (float*)d_out;

  float* sums  = (float*)d_ws;       // sum_h(512), sum_v(512)
  float* sum_h = sums;
  float* sum_v = sums + 512;
  __hip_bfloat16* hbuf = (__hip_bfloat16*)((char*)d_ws + 32768);
  __hip_bfloat16* vbuf = hbuf + (size_t)4 * CCH * HW;

  hipMemsetAsync(d_ws, 0, 1024 * sizeof(float), stream);
  conv_kernel<<<12288, 256, 0, stream>>>(x, h1w, h2w, v1w, v2w, hbuf, vbuf, sum_h, sum_v);
  fuse_kernel<<<4 * HGT * 2, 256, 0, stream>>>(x, hbuf, vbuf, fusew, fuseb,
                                               g1w, g2w, g2b, sum_h, sum_v, out);
}